// Round 1
// baseline (169.467 us; speedup 1.0000x reference)
//
#include <hip/hip_runtime.h>
#include <math.h>

#define N_NODE 50000
#define D_FEAT 128
#define N_EDGE 625000
#define SIM_THRESH 0.1f

// ---------------------------------------------------------------------------
// Kernel 1: per-node inverse L2 norm. 32 lanes per node, one float4 per lane
// (32 x 4 floats = 128 = D_FEAT). Fully coalesced 512B row reads.
// ---------------------------------------------------------------------------
__global__ void inv_norm_kernel(const float* __restrict__ feat,
                                float* __restrict__ inv_nrm) {
    int g = blockIdx.x * blockDim.x + threadIdx.x;
    int node = g >> 5;
    int lane = g & 31;
    if (node >= N_NODE) return;
    const float4* f = (const float4*)(feat + (size_t)node * D_FEAT);
    float4 v = f[lane];
    float ss = v.x * v.x + v.y * v.y + v.z * v.z + v.w * v.w;
#pragma unroll
    for (int o = 16; o > 0; o >>= 1)
        ss += __shfl_down(ss, o, 32);
    if (lane == 0) {
        float n = fmaxf(sqrtf(ss), 1e-12f);
        inv_nrm[node] = 1.0f / n;
    }
}

// ---------------------------------------------------------------------------
// Kernel 2: per-edge cosine sim + threshold, accumulate row_sum and degree.
// 32 lanes per edge. sim >= 0 after threshold, so |sim| == sim, and
// degree counts sim != 0 (denominator is always > 0 when sim != 0, so
// sim_norm != 0  <=>  sim != 0).
// ---------------------------------------------------------------------------
__global__ void edge_sim_kernel(const int* __restrict__ row,
                                const int* __restrict__ col,
                                const float* __restrict__ feat,
                                const float* __restrict__ inv_nrm,
                                float* __restrict__ sim_out,
                                float* __restrict__ row_sum,
                                float* __restrict__ degree) {
    int g = blockIdx.x * blockDim.x + threadIdx.x;
    int edge = g >> 5;
    int lane = g & 31;
    if (edge >= N_EDGE) return;
    int r = row[edge];
    int c = col[edge];
    const float4* fr = (const float4*)(feat + (size_t)r * D_FEAT);
    const float4* fc = (const float4*)(feat + (size_t)c * D_FEAT);
    float4 a = fr[lane];
    float4 b = fc[lane];
    float d = a.x * b.x + a.y * b.y + a.z * b.z + a.w * b.w;
#pragma unroll
    for (int o = 16; o > 0; o >>= 1)
        d += __shfl_down(d, o, 32);
    if (lane == 0) {
        float s = d * inv_nrm[r] * inv_nrm[c];
        if (s < SIM_THRESH) s = 0.0f;
        sim_out[edge] = s;
        if (s != 0.0f) {
            atomicAdd(&row_sum[r], s);
            atomicAdd(&degree[r], 1.0f);
        }
    }
}

// ---------------------------------------------------------------------------
// Kernel 3: epilogue. sim_norm = sim/denom, optional diagonal lam, exp,
// gate blend, clamp. One thread per edge, fully streaming.
// ---------------------------------------------------------------------------
__global__ void edge_out_kernel(const int* __restrict__ row,
                                const int* __restrict__ col,
                                const float* __restrict__ sim,
                                const float* __restrict__ row_sum,
                                const float* __restrict__ degree,
                                const float* __restrict__ ew,
                                const float* __restrict__ gate,
                                float* __restrict__ out) {
    int e = blockIdx.x * blockDim.x + threadIdx.x;
    if (e >= N_EDGE) return;
    int r = row[e];
    float rs = row_sum[r];
    float denom = (rs > 0.0f) ? rs : 1.0f;
    float att = sim[e] / denom;
    if (r == col[e]) att += 1.0f / (degree[r] + 1.0f);
    att = expf(att);
    float gv = gate[0];
    float o = gv * ew[e] + (1.0f - gv) * att;
    out[e] = fmaxf(o, 0.0f);
}

// ---------------------------------------------------------------------------
// Launch
// ---------------------------------------------------------------------------
extern "C" void kernel_launch(void* const* d_in, const int* in_sizes, int n_in,
                              void* d_out, int out_size, void* d_ws, size_t ws_size,
                              hipStream_t stream) {
    const int*   edge_index = (const int*)d_in[0];   // [2, E] row-major: row then col
    const float* ew         = (const float*)d_in[1];
    const float* feat       = (const float*)d_in[2];
    const float* gate       = (const float*)d_in[3];
    float*       out        = (float*)d_out;

    // Workspace layout (floats): row_sum[N] | degree[N] | inv_nrm[N] | sim[E]
    float* row_sum = (float*)d_ws;
    float* degree  = row_sum + N_NODE;
    float* inv_nrm = degree + N_NODE;
    float* sim     = inv_nrm + N_NODE;

    const int* row = edge_index;
    const int* col = edge_index + N_EDGE;

    // Zero the accumulators (ws is poisoned 0xAA before every call).
    hipMemsetAsync(d_ws, 0, (size_t)2 * N_NODE * sizeof(float), stream);

    {
        const int block = 256;
        const long long threads = (long long)N_NODE * 32;
        inv_norm_kernel<<<(int)((threads + block - 1) / block), block, 0, stream>>>(
            feat, inv_nrm);
    }
    {
        const int block = 256;
        const long long threads = (long long)N_EDGE * 32;
        edge_sim_kernel<<<(int)((threads + block - 1) / block), block, 0, stream>>>(
            row, col, feat, inv_nrm, sim, row_sum, degree);
    }
    {
        const int block = 256;
        edge_out_kernel<<<(N_EDGE + block - 1) / block, block, 0, stream>>>(
            row, col, sim, row_sum, degree, ew, gate, out);
    }
}

// Round 2
// 149.502 us; speedup vs baseline: 1.1335x; 1.1335x over previous
//
#include <hip/hip_runtime.h>
#include <hip/hip_fp16.h>
#include <math.h>

#define N_NODE 50000
#define D_FEAT 128
#define N_EDGE 625000
#define SIM_THRESH 0.1f
// fp16-induced sim error is <= ~2e-4; 1e-3 band is 5x conservative.
#define BAND_EPS 1e-3f

// ===========================================================================
// Fast path: fp16-compressed normalized features + exact fixup of edges whose
// fp16 sim lies within BAND_EPS of the 0.1 threshold.
// ===========================================================================

// K1: per-node inv-norm + write normalized fp16 features; also zero the
// row_sum/degree accumulators and the band counter (ws is poisoned 0xAA).
__global__ void prep_kernel(const float* __restrict__ feat,
                            float* __restrict__ inv_nrm,
                            __half* __restrict__ fn16,
                            float* __restrict__ row_sum,
                            float* __restrict__ degree,
                            unsigned int* __restrict__ band_count) {
    int g = blockIdx.x * blockDim.x + threadIdx.x;
    if (g < N_NODE) { row_sum[g] = 0.0f; degree[g] = 0.0f; }
    if (g == 0) *band_count = 0u;
    int node = g >> 5;
    int lane = g & 31;
    if (node >= N_NODE) return;
    const float4* f = (const float4*)(feat + (size_t)node * D_FEAT);
    float4 v = f[lane];
    float ss = v.x * v.x + v.y * v.y + v.z * v.z + v.w * v.w;
#pragma unroll
    for (int o = 16; o > 0; o >>= 1)
        ss += __shfl_down(ss, o, 32);
    ss = __shfl(ss, 0, 32);                       // broadcast total
    float inv = 1.0f / fmaxf(sqrtf(ss), 1e-12f);
    if (lane == 0) inv_nrm[node] = inv;
    __half2 h0 = __floats2half2_rn(v.x * inv, v.y * inv);
    __half2 h1 = __floats2half2_rn(v.z * inv, v.w * inv);
    __half2* dst = (__half2*)(fn16 + (size_t)node * D_FEAT);
    dst[lane * 2]     = h0;
    dst[lane * 2 + 1] = h1;
}

// K2: per-edge fp16 cosine sim. 16 lanes/edge, one float4 (=8 halves) per
// lane per endpoint. Near-threshold edges deferred to the exact fixup list.
__global__ void edge_sim16_kernel(const int* __restrict__ row,
                                  const int* __restrict__ col,
                                  const __half* __restrict__ fn16,
                                  float* __restrict__ sim_out,
                                  float* __restrict__ row_sum,
                                  float* __restrict__ degree,
                                  unsigned int* __restrict__ band_count,
                                  unsigned int* __restrict__ band_list) {
    int g = blockIdx.x * blockDim.x + threadIdx.x;
    int edge = g >> 4;
    int lane = g & 15;
    if (edge >= N_EDGE) return;
    int r = row[edge];
    int c = col[edge];
    float4 a = ((const float4*)(fn16 + (size_t)r * D_FEAT))[lane];
    float4 b = ((const float4*)(fn16 + (size_t)c * D_FEAT))[lane];
    const __half2* ah = (const __half2*)&a;
    const __half2* bh = (const __half2*)&b;
    float d = 0.0f;
#pragma unroll
    for (int i = 0; i < 4; i++) {
        float2 af = __half22float2(ah[i]);
        float2 bf = __half22float2(bh[i]);
        d = fmaf(af.x, bf.x, d);
        d = fmaf(af.y, bf.y, d);
    }
#pragma unroll
    for (int o = 8; o > 0; o >>= 1)
        d += __shfl_down(d, o, 16);
    if (lane == 0) {
        float s = d;
        if (fabsf(s - SIM_THRESH) < BAND_EPS) {
            unsigned int idx = atomicAdd(band_count, 1u);
            band_list[idx] = (unsigned int)edge;   // K3 writes sim + accum
        } else {
            if (s < SIM_THRESH) s = 0.0f;
            sim_out[edge] = s;
            if (s != 0.0f) {
                atomicAdd(&row_sum[r], s);
                atomicAdd(&degree[r], 1.0f);
            }
        }
    }
}

// K3: exact fp32 recompute of band edges (expected ~0.3% of E). Fixed grid,
// grid-stride over the device-side count.
__global__ void band_fix_kernel(const int* __restrict__ row,
                                const int* __restrict__ col,
                                const float* __restrict__ feat,
                                const float* __restrict__ inv_nrm,
                                const unsigned int* __restrict__ band_count,
                                const unsigned int* __restrict__ band_list,
                                float* __restrict__ sim_out,
                                float* __restrict__ row_sum,
                                float* __restrict__ degree) {
    int g = blockIdx.x * blockDim.x + threadIdx.x;
    int group = g >> 5;
    int lane = g & 31;
    int ngroups = (gridDim.x * blockDim.x) >> 5;
    unsigned int cnt = *band_count;
    for (unsigned int i = group; i < cnt; i += ngroups) {
        int e = (int)band_list[i];
        int r = row[e], c = col[e];
        float4 a = ((const float4*)(feat + (size_t)r * D_FEAT))[lane];
        float4 b = ((const float4*)(feat + (size_t)c * D_FEAT))[lane];
        float d = a.x * b.x + a.y * b.y + a.z * b.z + a.w * b.w;
#pragma unroll
        for (int o = 16; o > 0; o >>= 1)
            d += __shfl_down(d, o, 32);
        if (lane == 0) {
            float s = d * inv_nrm[r] * inv_nrm[c];
            if (s < SIM_THRESH) s = 0.0f;
            sim_out[e] = s;
            if (s != 0.0f) {
                atomicAdd(&row_sum[r], s);
                atomicAdd(&degree[r], 1.0f);
            }
        }
    }
}

// K4: epilogue — normalize, diagonal lam, exp, gate blend, clamp.
__global__ void edge_out_kernel(const int* __restrict__ row,
                                const int* __restrict__ col,
                                const float* __restrict__ sim,
                                const float* __restrict__ row_sum,
                                const float* __restrict__ degree,
                                const float* __restrict__ ew,
                                const float* __restrict__ gate,
                                float* __restrict__ out) {
    int e = blockIdx.x * blockDim.x + threadIdx.x;
    if (e >= N_EDGE) return;
    int r = row[e];
    float rs = row_sum[r];
    float denom = (rs > 0.0f) ? rs : 1.0f;
    float att = sim[e] / denom;
    if (r == col[e]) att += 1.0f / (degree[r] + 1.0f);
    att = expf(att);
    float gv = gate[0];
    float o = gv * ew[e] + (1.0f - gv) * att;
    out[e] = fmaxf(o, 0.0f);
}

// ===========================================================================
// Fallback path (pure fp32, round-1 version) if ws is too small for fn16.
// ===========================================================================
__global__ void inv_norm_kernel(const float* __restrict__ feat,
                                float* __restrict__ inv_nrm) {
    int g = blockIdx.x * blockDim.x + threadIdx.x;
    int node = g >> 5;
    int lane = g & 31;
    if (node >= N_NODE) return;
    const float4* f = (const float4*)(feat + (size_t)node * D_FEAT);
    float4 v = f[lane];
    float ss = v.x * v.x + v.y * v.y + v.z * v.z + v.w * v.w;
#pragma unroll
    for (int o = 16; o > 0; o >>= 1)
        ss += __shfl_down(ss, o, 32);
    if (lane == 0) {
        float n = fmaxf(sqrtf(ss), 1e-12f);
        inv_nrm[node] = 1.0f / n;
    }
}

__global__ void edge_sim_kernel(const int* __restrict__ row,
                                const int* __restrict__ col,
                                const float* __restrict__ feat,
                                const float* __restrict__ inv_nrm,
                                float* __restrict__ sim_out,
                                float* __restrict__ row_sum,
                                float* __restrict__ degree) {
    int g = blockIdx.x * blockDim.x + threadIdx.x;
    int edge = g >> 5;
    int lane = g & 31;
    if (edge >= N_EDGE) return;
    int r = row[edge];
    int c = col[edge];
    float4 a = ((const float4*)(feat + (size_t)r * D_FEAT))[lane];
    float4 b = ((const float4*)(feat + (size_t)c * D_FEAT))[lane];
    float d = a.x * b.x + a.y * b.y + a.z * b.z + a.w * b.w;
#pragma unroll
    for (int o = 16; o > 0; o >>= 1)
        d += __shfl_down(d, o, 32);
    if (lane == 0) {
        float s = d * inv_nrm[r] * inv_nrm[c];
        if (s < SIM_THRESH) s = 0.0f;
        sim_out[edge] = s;
        if (s != 0.0f) {
            atomicAdd(&row_sum[r], s);
            atomicAdd(&degree[r], 1.0f);
        }
    }
}

// ===========================================================================
// Launch
// ===========================================================================
extern "C" void kernel_launch(void* const* d_in, const int* in_sizes, int n_in,
                              void* d_out, int out_size, void* d_ws, size_t ws_size,
                              hipStream_t stream) {
    const int*   edge_index = (const int*)d_in[0];   // [2, E]: row then col
    const float* ew         = (const float*)d_in[1];
    const float* feat       = (const float*)d_in[2];
    const float* gate       = (const float*)d_in[3];
    float*       out        = (float*)d_out;

    const int* row = edge_index;
    const int* col = edge_index + N_EDGE;

    // Workspace layout (all offsets 16B-aligned):
    //   row_sum[N] | degree[N] | inv_nrm[N] | sim[E] | fn16[N*128 halves]
    //   | band_list[E] | band_count[1]
    float* row_sum = (float*)d_ws;
    float* degree  = row_sum + N_NODE;
    float* inv_nrm = degree + N_NODE;
    float* sim     = inv_nrm + N_NODE;
    __half* fn16   = (__half*)(sim + N_EDGE);
    unsigned int* band_list  = (unsigned int*)(fn16 + (size_t)N_NODE * D_FEAT);
    unsigned int* band_count = band_list + N_EDGE;

    size_t need = (size_t)(3 * N_NODE + N_EDGE) * 4
                + (size_t)N_NODE * D_FEAT * 2
                + (size_t)(N_EDGE + 1) * 4;

    const int block = 256;

    if (ws_size >= need) {
        // ---- fast fp16 path ----
        {
            long long threads = (long long)N_NODE * 32;
            prep_kernel<<<(int)((threads + block - 1) / block), block, 0, stream>>>(
                feat, inv_nrm, fn16, row_sum, degree, band_count);
        }
        {
            long long threads = (long long)N_EDGE * 16;
            edge_sim16_kernel<<<(int)((threads + block - 1) / block), block, 0, stream>>>(
                row, col, fn16, sim, row_sum, degree, band_count, band_list);
        }
        band_fix_kernel<<<64, block, 0, stream>>>(
            row, col, feat, inv_nrm, band_count, band_list, sim, row_sum, degree);
        edge_out_kernel<<<(N_EDGE + block - 1) / block, block, 0, stream>>>(
            row, col, sim, row_sum, degree, ew, gate, out);
    } else {
        // ---- fp32 fallback ----
        hipMemsetAsync(d_ws, 0, (size_t)2 * N_NODE * sizeof(float), stream);
        {
            long long threads = (long long)N_NODE * 32;
            inv_norm_kernel<<<(int)((threads + block - 1) / block), block, 0, stream>>>(
                feat, inv_nrm);
        }
        {
            long long threads = (long long)N_EDGE * 32;
            edge_sim_kernel<<<(int)((threads + block - 1) / block), block, 0, stream>>>(
                row, col, feat, inv_nrm, sim, row_sum, degree);
        }
        edge_out_kernel<<<(N_EDGE + block - 1) / block, block, 0, stream>>>(
            row, col, sim, row_sum, degree, ew, gate, out);
    }
}